// Round 12
// baseline (173.350 us; speedup 1.0000x reference)
//
#include <hip/hip_runtime.h>
#include <hip/hip_bf16.h>

#define NN 50000
#define NE 625000
#define CH 128
#define CAP 64       // per-row CSR capacity (max degree ~35)
#define NB 3125      // buckets of 16 rows: 3125*16 = 50000
#define NBP 3136     // padded bucket stride (per partition)
#define SCAP 64      // per-(partition,bucket) staging capacity; mean ~25

typedef __attribute__((ext_vector_type(8))) short short8;
typedef __attribute__((ext_vector_type(4))) float floatx4;

__device__ __forceinline__ ushort f2bf(float v) {
    __hip_bfloat16 h = __float2bfloat16(v);
    return *(ushort*)&h;
}
__device__ __forceinline__ float bf2f(uint u) {
    return __uint_as_float(u << 16);
}
__device__ __forceinline__ float inv_sqrt_deg(int d) {
    return (d > 0) ? rsqrtf((float)d) : 0.0f;
}

// ---------------- fused prep ----------------
// blocks [0,306):     phase-1 edge binning: stage[part][row>>4] <- (row<<16)|col
// blocks [306,6556):  cast x -> bf16 (4 f32/thr)
// blocks [6556,6620): W -> bf16 hi/lo split
__global__ __launch_bounds__(256) void k_prep(const float* __restrict__ x,
                                              ushort* __restrict__ xb,
                                              const float* __restrict__ W,
                                              ushort* __restrict__ whi,
                                              ushort* __restrict__ wlo,
                                              const int* __restrict__ row,
                                              const int* __restrict__ col,
                                              int* __restrict__ bcnt,
                                              uint* __restrict__ stage) {
    int b = blockIdx.x;
    if (b < 306) {
        int t = b * 256 + threadIdx.x;
        if (t < NE / 8) {                        // 78125 threads
            const int part = b & 7;              // round-robin ~ XCD id
            int* pb = bcnt + part * NBP;
            uint* ps = stage + ((size_t)part * NBP << 6);
            const int4* r8 = (const int4*)(row + t * 8);
            const int4* c8 = (const int4*)(col + t * 8);
            int4 ra = r8[0], rb = r8[1];
            int4 ca = c8[0], cb = c8[1];
            int r[8] = {ra.x, ra.y, ra.z, ra.w, rb.x, rb.y, rb.z, rb.w};
            int c[8] = {ca.x, ca.y, ca.z, ca.w, cb.x, cb.y, cb.z, cb.w};
            int s[8];
#pragma unroll
            for (int j = 0; j < 8; ++j) s[j] = atomicAdd(&pb[r[j] >> 4], 1);
#pragma unroll
            for (int j = 0; j < 8; ++j) {
                if (s[j] < SCAP)
                    ps[((r[j] >> 4) << 6) + s[j]] = ((uint)r[j] << 16) | (uint)c[j];
            }
        }
    } else if (b < 6556) {
        int i = ((b - 306) * 256 + threadIdx.x) * 4;   // 6,400,000 elems exactly
        float4 v = *(const float4*)(x + i);
        ushort4 o;
        o.x = f2bf(v.x); o.y = f2bf(v.y); o.z = f2bf(v.z); o.w = f2bf(v.w);
        *(ushort4*)(xb + i) = o;
    } else {
        int i = (b - 6556) * 256 + threadIdx.x;        // 16384 elems exactly
        float v = W[i];
        ushort h = f2bf(v);
        whi[i] = h;
        wlo[i] = f2bf(v - bf2f((uint)h));
    }
}

// ---------------- phase-2: merge partition buckets -> CSR (dense writes) ----------------
// One wave per bucket (16 rows). LDS slot counters; all ecol writes land in the
// bucket's 2KB window. Also emits cur[] (per-row degree) -> no cur memset needed.
__global__ __launch_bounds__(256) void k_csr(const int* __restrict__ bcnt,
                                             const uint* __restrict__ stage,
                                             int* __restrict__ cur,
                                             ushort* __restrict__ ecol) {
    __shared__ int cnts[4][16];
    const int wave = threadIdx.x >> 6;
    const int lane = threadIdx.x & 63;
    const int bucket = blockIdx.x * 4 + wave;
    if (bucket >= NB) return;                    // whole-wave exit; no barriers used
    if (lane < 16) cnts[wave][lane] = 0;
    // per-wave DS ordering guarantees zeros are visible before the atomics below
    for (int p = 0; p < 8; ++p) {
        int n = bcnt[p * NBP + bucket];
        n = (n > SCAP) ? SCAP : n;
        if (lane < n) {
            uint pk = stage[(((size_t)p * NBP + bucket) << 6) + lane];
            int r = (int)(pk >> 16);
            int c = (int)(pk & 0xFFFFu);
            int slot = atomicAdd(&cnts[wave][r & 15], 1);
            ecol[(r << 6) + slot] = (ushort)c;
        }
    }
    if (lane < 16) cur[bucket * 16 + lane] = cnts[wave][lane];
}

// ---------------- aggregation: one wave per node, lane-parallel prologue ----------------
__global__ __launch_bounds__(256) void k_agg(const ushort* __restrict__ xb,
                                             const int* __restrict__ cnt,
                                             const ushort* __restrict__ ecol,
                                             ushort* __restrict__ ahi) {
    const int wave = threadIdx.x >> 6;
    const int lane = threadIdx.x & 63;
    const int node = blockIdx.x * 4 + wave;
    const int deg = cnt[node];
    const float dr = inv_sqrt_deg(deg);

    ushort craw = ecol[(node << 6) + lane];           // coalesced 128B per wave
    int cli = (lane < deg) ? (int)craw : 0;
    float nl = (lane < deg) ? inv_sqrt_deg(cnt[cli]) : 0.0f;

    float ax = 0.0f, ay = 0.0f;
    for (int j = 0; j < deg; j += 8) {
#pragma unroll
        for (int u = 0; u < 8; ++u) {
            int cc = __shfl(cli, j + u);
            float nn = __shfl(nl, j + u);             // 0 for slots >= deg
            ushort2 v = ((const ushort2*)(xb + (size_t)cc * CH))[lane];
            ax = fmaf(bf2f((uint)v.x), nn, ax);
            ay = fmaf(bf2f((uint)v.y), nn, ay);
        }
    }

    ushort2 hv;
    hv.x = f2bf(ax * dr);
    hv.y = f2bf(ay * dr);
    ((ushort2*)(ahi + (size_t)node * CH))[lane] = hv;
}

// ---------------- MFMA GEMM: out = Ahi @ (Whi+Wlo)^T + b ----------------
__global__ __launch_bounds__(256) void k_mfma(const ushort* __restrict__ ahi,
                                              const ushort* __restrict__ whi,
                                              const ushort* __restrict__ wlo,
                                              const float* __restrict__ bias,
                                              float* __restrict__ out) {
    const int wave = threadIdx.x >> 6;
    const int lane = threadIdx.x & 63;
    const int quad = lane >> 4;
    const int r16 = lane & 15;
    const int m0 = blockIdx.x * 16;            // 3125 blocks exactly
    const int nt0 = wave * 2, nt1 = nt0 + 1;

    const ushort* ap   = ahi + (size_t)(m0 + r16) * CH + quad * 8;
    const ushort* bh0p = whi + (size_t)(nt0 * 16 + r16) * CH + quad * 8;
    const ushort* bl0p = wlo + (size_t)(nt0 * 16 + r16) * CH + quad * 8;
    const ushort* bh1p = whi + (size_t)(nt1 * 16 + r16) * CH + quad * 8;
    const ushort* bl1p = wlo + (size_t)(nt1 * 16 + r16) * CH + quad * 8;

    float b0 = bias[nt0 * 16 + r16];
    float b1 = bias[nt1 * 16 + r16];
    floatx4 acc0 = {b0, b0, b0, b0};
    floatx4 acc1 = {b1, b1, b1, b1};

#pragma unroll
    for (int kb = 0; kb < 4; ++kb) {
        const int k0 = kb * 32;
        short8 a  = *(const short8*)(ap + k0);
        short8 h0 = *(const short8*)(bh0p + k0);
        short8 l0 = *(const short8*)(bl0p + k0);
        short8 h1 = *(const short8*)(bh1p + k0);
        short8 l1 = *(const short8*)(bl1p + k0);
        acc0 = __builtin_amdgcn_mfma_f32_16x16x32_bf16(a, h0, acc0, 0, 0, 0);
        acc0 = __builtin_amdgcn_mfma_f32_16x16x32_bf16(a, l0, acc0, 0, 0, 0);
        acc1 = __builtin_amdgcn_mfma_f32_16x16x32_bf16(a, h1, acc1, 0, 0, 0);
        acc1 = __builtin_amdgcn_mfma_f32_16x16x32_bf16(a, l1, acc1, 0, 0, 0);
    }

#pragma unroll
    for (int r = 0; r < 4; ++r) {
        int row = m0 + quad * 4 + r;
        out[(size_t)row * CH + nt0 * 16 + r16] = acc0[r];
        out[(size_t)row * CH + nt1 * 16 + r16] = acc1[r];
    }
}

extern "C" void kernel_launch(void* const* d_in, const int* in_sizes, int n_in,
                              void* d_out, int out_size, void* d_ws, size_t ws_size,
                              hipStream_t stream) {
    const float* x = (const float*)d_in[0];
    const int* ei = (const int*)d_in[1]; // [2, NE]: row = ei, col = ei + NE
    const float* W = (const float*)d_in[2];
    const float* b = (const float*)d_in[3];
    float* out = (float*)d_out;

    // ws: [bcnt 8*NBP int][stage 8*NBP*64 uint][cur 50176 int][ecol NN*64 ushort]
    //     [xb NN*CH u16][ahi NN*CH u16][whi 16384 u16][wlo 16384 u16]   ~39 MB
    int* bcnt = (int*)d_ws;
    uint* stage = (uint*)(bcnt + 8 * NBP);
    int* cur = (int*)(stage + ((size_t)8 * NBP << 6));
    ushort* ecol = (ushort*)(cur + 50176);
    ushort* xb = ecol + (size_t)NN * CAP;
    ushort* ahi = xb + (size_t)NN * CH;
    ushort* whi = ahi + (size_t)NN * CH;
    ushort* wlo = whi + CH * CH;

    hipMemsetAsync(bcnt, 0, (size_t)8 * NBP * sizeof(int), stream);
    k_prep<<<6620, 256, 0, stream>>>(x, xb, W, whi, wlo, ei, ei + NE, bcnt, stage);
    k_csr<<<(NB + 3) / 4, 256, 0, stream>>>(bcnt, stage, cur, ecol);
    k_agg<<<NN / 4, 256, 0, stream>>>(xb, cur, ecol, ahi);
    k_mfma<<<NN / 16, 256, 0, stream>>>(ahi, whi, wlo, b, out);
}

// Round 13
// 168.451 us; speedup vs baseline: 1.0291x; 1.0291x over previous
//
#include <hip/hip_runtime.h>
#include <hip/hip_bf16.h>

#define NN 50000
#define NE 625000
#define CH 128
#define CAP 64       // per-row CSR capacity (max degree ~35)
#define CSTR 16      // cur stride in ints: 1 counter per 64B line (atomic anti-serialization)

typedef __attribute__((ext_vector_type(8))) short short8;
typedef __attribute__((ext_vector_type(4))) float floatx4;

__device__ __forceinline__ ushort f2bf(float v) {
    __hip_bfloat16 h = __float2bfloat16(v);
    return *(ushort*)&h;
}
__device__ __forceinline__ float bf2f(uint u) {
    return __uint_as_float(u << 16);
}
__device__ __forceinline__ float inv_sqrt_deg(int d) {
    return (d > 0) ? rsqrtf((float)d) : 0.0f;
}

// ---------------- fused prep ----------------
// blocks [0,306):     CSR fill, 8 edges/thread; atomic counters padded to 1/line
// blocks [306,6556):  cast x -> bf16 (4 f32/thr)
// blocks [6556,6620): W -> bf16 hi/lo split
__global__ __launch_bounds__(256) void k_prep(const float* __restrict__ x,
                                              ushort* __restrict__ xb,
                                              const float* __restrict__ W,
                                              ushort* __restrict__ whi,
                                              ushort* __restrict__ wlo,
                                              const int* __restrict__ row,
                                              const int* __restrict__ col,
                                              int* __restrict__ curp,
                                              ushort* __restrict__ ecol) {
    int b = blockIdx.x;
    if (b < 306) {
        int t = b * 256 + threadIdx.x;
        if (t < NE / 8) {                        // 78125 threads
            const int4* r8 = (const int4*)(row + t * 8);
            const int4* c8 = (const int4*)(col + t * 8);
            int4 ra = r8[0], rb = r8[1];
            int4 ca = c8[0], cb = c8[1];
            int p0 = atomicAdd(&curp[ra.x * CSTR], 1);
            int p1 = atomicAdd(&curp[ra.y * CSTR], 1);
            int p2 = atomicAdd(&curp[ra.z * CSTR], 1);
            int p3 = atomicAdd(&curp[ra.w * CSTR], 1);
            int p4 = atomicAdd(&curp[rb.x * CSTR], 1);
            int p5 = atomicAdd(&curp[rb.y * CSTR], 1);
            int p6 = atomicAdd(&curp[rb.z * CSTR], 1);
            int p7 = atomicAdd(&curp[rb.w * CSTR], 1);
            ecol[(ra.x << 6) + p0] = (ushort)ca.x;
            ecol[(ra.y << 6) + p1] = (ushort)ca.y;
            ecol[(ra.z << 6) + p2] = (ushort)ca.z;
            ecol[(ra.w << 6) + p3] = (ushort)ca.w;
            ecol[(rb.x << 6) + p4] = (ushort)cb.x;
            ecol[(rb.y << 6) + p5] = (ushort)cb.y;
            ecol[(rb.z << 6) + p6] = (ushort)cb.z;
            ecol[(rb.w << 6) + p7] = (ushort)cb.w;
        }
    } else if (b < 6556) {
        int i = ((b - 306) * 256 + threadIdx.x) * 4;   // 6,400,000 elems exactly
        float4 v = *(const float4*)(x + i);
        ushort4 o;
        o.x = f2bf(v.x); o.y = f2bf(v.y); o.z = f2bf(v.z); o.w = f2bf(v.w);
        *(ushort4*)(xb + i) = o;
    } else {
        int i = (b - 6556) * 256 + threadIdx.x;        // 16384 elems exactly
        float v = W[i];
        ushort h = f2bf(v);
        whi[i] = h;
        wlo[i] = f2bf(v - bf2f((uint)h));
    }
}

// ---------------- compact degrees + precompute norms ----------------
// deg_c[i] = curp[i*CSTR]; nrm[i] = deg^-1/2 (f32). 50176 threads.
__global__ __launch_bounds__(256) void k_nrm(const int* __restrict__ curp,
                                             int* __restrict__ deg_c,
                                             float* __restrict__ nrm) {
    int i = blockIdx.x * 256 + threadIdx.x;          // 196 blocks * 256 = 50176
    int d = curp[i * CSTR];
    deg_c[i] = d;
    nrm[i] = inv_sqrt_deg(d);
}

// ---------------- aggregation: one wave per node, lane-parallel prologue ----------------
// Prologue: lane l loads CSR slot l (coalesced), gathers nrm (pre-rsqrt'd).
// Main loop (predicated unroll-8, no tail): shfl(col), shfl(norm), xb row gather, fma.
__global__ __launch_bounds__(256) void k_agg(const ushort* __restrict__ xb,
                                             const int* __restrict__ deg_c,
                                             const float* __restrict__ nrm,
                                             const ushort* __restrict__ ecol,
                                             ushort* __restrict__ ahi) {
    const int wave = threadIdx.x >> 6;
    const int lane = threadIdx.x & 63;
    const int node = blockIdx.x * 4 + wave;
    const int deg = deg_c[node];
    const float dr = nrm[node];

    ushort craw = ecol[(node << 6) + lane];           // coalesced 128B per wave
    int cli = (lane < deg) ? (int)craw : 0;
    float nl = (lane < deg) ? nrm[cli] : 0.0f;

    float ax = 0.0f, ay = 0.0f;
    for (int j = 0; j < deg; j += 8) {
#pragma unroll
        for (int u = 0; u < 8; ++u) {
            int cc = __shfl(cli, j + u);
            float nn = __shfl(nl, j + u);             // 0 for slots >= deg
            ushort2 v = ((const ushort2*)(xb + (size_t)cc * CH))[lane];
            ax = fmaf(bf2f((uint)v.x), nn, ax);
            ay = fmaf(bf2f((uint)v.y), nn, ay);
        }
    }

    ushort2 hv;
    hv.x = f2bf(ax * dr);
    hv.y = f2bf(ay * dr);
    ((ushort2*)(ahi + (size_t)node * CH))[lane] = hv;
}

// ---------------- MFMA GEMM: out = Ahi @ (Whi+Wlo)^T + b ----------------
// 16x16x32 bf16 fragments straight from global (no LDS).
__global__ __launch_bounds__(256) void k_mfma(const ushort* __restrict__ ahi,
                                              const ushort* __restrict__ whi,
                                              const ushort* __restrict__ wlo,
                                              const float* __restrict__ bias,
                                              float* __restrict__ out) {
    const int wave = threadIdx.x >> 6;
    const int lane = threadIdx.x & 63;
    const int quad = lane >> 4;
    const int r16 = lane & 15;
    const int m0 = blockIdx.x * 16;            // 3125 blocks exactly
    const int nt0 = wave * 2, nt1 = nt0 + 1;

    const ushort* ap   = ahi + (size_t)(m0 + r16) * CH + quad * 8;
    const ushort* bh0p = whi + (size_t)(nt0 * 16 + r16) * CH + quad * 8;
    const ushort* bl0p = wlo + (size_t)(nt0 * 16 + r16) * CH + quad * 8;
    const ushort* bh1p = whi + (size_t)(nt1 * 16 + r16) * CH + quad * 8;
    const ushort* bl1p = wlo + (size_t)(nt1 * 16 + r16) * CH + quad * 8;

    float b0 = bias[nt0 * 16 + r16];
    float b1 = bias[nt1 * 16 + r16];
    floatx4 acc0 = {b0, b0, b0, b0};
    floatx4 acc1 = {b1, b1, b1, b1};

#pragma unroll
    for (int kb = 0; kb < 4; ++kb) {
        const int k0 = kb * 32;
        short8 a  = *(const short8*)(ap + k0);
        short8 h0 = *(const short8*)(bh0p + k0);
        short8 l0 = *(const short8*)(bl0p + k0);
        short8 h1 = *(const short8*)(bh1p + k0);
        short8 l1 = *(const short8*)(bl1p + k0);
        acc0 = __builtin_amdgcn_mfma_f32_16x16x32_bf16(a, h0, acc0, 0, 0, 0);
        acc0 = __builtin_amdgcn_mfma_f32_16x16x32_bf16(a, l0, acc0, 0, 0, 0);
        acc1 = __builtin_amdgcn_mfma_f32_16x16x32_bf16(a, h1, acc1, 0, 0, 0);
        acc1 = __builtin_amdgcn_mfma_f32_16x16x32_bf16(a, l1, acc1, 0, 0, 0);
    }

#pragma unroll
    for (int r = 0; r < 4; ++r) {
        int row = m0 + quad * 4 + r;
        out[(size_t)row * CH + nt0 * 16 + r16] = acc0[r];
        out[(size_t)row * CH + nt1 * 16 + r16] = acc1[r];
    }
}

extern "C" void kernel_launch(void* const* d_in, const int* in_sizes, int n_in,
                              void* d_out, int out_size, void* d_ws, size_t ws_size,
                              hipStream_t stream) {
    const float* x = (const float*)d_in[0];
    const int* ei = (const int*)d_in[1]; // [2, NE]: row = ei, col = ei + NE
    const float* W = (const float*)d_in[2];
    const float* b = (const float*)d_in[3];
    float* out = (float*)d_out;

    // ws: [curp 50176*16 int (3.2MB, 1 counter/64B line)][deg_c 50176 int][nrm 50176 f32]
    //     [ecol NN*64 ushort][xb NN*CH u16][ahi NN*CH u16][whi 16384 u16][wlo 16384 u16]
    int* curp = (int*)d_ws;
    int* deg_c = curp + 50176 * CSTR;
    float* nrm = (float*)(deg_c + 50176);
    ushort* ecol = (ushort*)(nrm + 50176);
    ushort* xb = ecol + (size_t)NN * CAP;
    ushort* ahi = xb + (size_t)NN * CH;
    ushort* whi = ahi + (size_t)NN * CH;
    ushort* wlo = whi + CH * CH;

    hipMemsetAsync(curp, 0, (size_t)50176 * CSTR * sizeof(int), stream);
    k_prep<<<6620, 256, 0, stream>>>(x, xb, W, whi, wlo, ei, ei + NE, curp, ecol);
    k_nrm<<<196, 256, 0, stream>>>(curp, deg_c, nrm);
    k_agg<<<NN / 4, 256, 0, stream>>>(xb, deg_c, nrm, ecol, ahi);
    k_mfma<<<NN / 16, 256, 0, stream>>>(ahi, whi, wlo, b, out);
}

// Round 14
// 161.800 us; speedup vs baseline: 1.0714x; 1.0411x over previous
//
#include <hip/hip_runtime.h>
#include <hip/hip_bf16.h>

#define NN 50000
#define NE 625000
#define CH 128
// CSR row block: 32 uints = 128B = [u32 deg][62 ushort slots]; max degree ~38 << 62
#define RSTR 32

typedef __attribute__((ext_vector_type(8))) short short8;
typedef __attribute__((ext_vector_type(4))) float floatx4;

__device__ __forceinline__ ushort f2bf(float v) {
    __hip_bfloat16 h = __float2bfloat16(v);
    return *(ushort*)&h;
}
__device__ __forceinline__ float bf2f(uint u) {
    return __uint_as_float(u << 16);
}
__device__ __forceinline__ float inv_sqrt_deg(int d) {
    return (d > 0) ? rsqrtf((float)d) : 0.0f;
}

// ---------------- fused prep ----------------
// blocks [0,306):     CSR fill, 8 edges/thread; counter EMBEDDED in row block
//                     (atomic + slot store hit the same 64B line for deg<30)
// blocks [306,6556):  cast x -> bf16 (4 f32/thr)
// blocks [6556,6620): W -> bf16 hi/lo split
__global__ __launch_bounds__(256) void k_prep(const float* __restrict__ x,
                                              ushort* __restrict__ xb,
                                              const float* __restrict__ W,
                                              ushort* __restrict__ whi,
                                              ushort* __restrict__ wlo,
                                              const int* __restrict__ row,
                                              const int* __restrict__ col,
                                              uint* __restrict__ csr) {
    int b = blockIdx.x;
    if (b < 306) {
        int t = b * 256 + threadIdx.x;
        if (t < NE / 8) {                        // 78125 threads
            const int4* r8 = (const int4*)(row + t * 8);
            const int4* c8 = (const int4*)(col + t * 8);
            int4 ra = r8[0], rb = r8[1];
            int4 ca = c8[0], cb = c8[1];
            int r[8] = {ra.x, ra.y, ra.z, ra.w, rb.x, rb.y, rb.z, rb.w};
            int c[8] = {ca.x, ca.y, ca.z, ca.w, cb.x, cb.y, cb.z, cb.w};
            int p[8];
#pragma unroll
            for (int j = 0; j < 8; ++j)
                p[j] = (int)atomicAdd(&csr[r[j] * RSTR], 1u);
#pragma unroll
            for (int j = 0; j < 8; ++j) {
                if (p[j] < 62)
                    ((ushort*)(csr + r[j] * RSTR))[2 + p[j]] = (ushort)c[j];
            }
        }
    } else if (b < 6556) {
        int i = ((b - 306) * 256 + threadIdx.x) * 4;   // 6,400,000 elems exactly
        float4 v = *(const float4*)(x + i);
        ushort4 o;
        o.x = f2bf(v.x); o.y = f2bf(v.y); o.z = f2bf(v.z); o.w = f2bf(v.w);
        *(ushort4*)(xb + i) = o;
    } else {
        int i = (b - 6556) * 256 + threadIdx.x;        // 16384 elems exactly
        float v = W[i];
        ushort h = f2bf(v);
        whi[i] = h;
        wlo[i] = f2bf(v - bf2f((uint)h));
    }
}

// ---------------- compact degrees + precompute norms ----------------
__global__ __launch_bounds__(256) void k_nrm(const uint* __restrict__ csr,
                                             int* __restrict__ deg_c,
                                             float* __restrict__ nrm) {
    int i = blockIdx.x * 256 + threadIdx.x;          // 196 * 256 = 50176
    if (i < NN) {
        int d = (int)csr[i * RSTR];
        deg_c[i] = d;
        nrm[i] = inv_sqrt_deg(d);
    } else if (i < 50176) {
        deg_c[i] = 0;
        nrm[i] = 0.0f;
    }
}

// ---------------- aggregation: one wave per node, lane-parallel prologue ----------------
__global__ __launch_bounds__(256) void k_agg(const ushort* __restrict__ xb,
                                             const int* __restrict__ deg_c,
                                             const float* __restrict__ nrm,
                                             const uint* __restrict__ csr,
                                             ushort* __restrict__ ahi) {
    const int wave = threadIdx.x >> 6;
    const int lane = threadIdx.x & 63;
    const int node = blockIdx.x * 4 + wave;
    const int deg = deg_c[node];
    const float dr = nrm[node];

    // lane-parallel prologue over the node's <=62 slots (safe-clamped address)
    const ushort* slots = (const ushort*)(csr + node * RSTR) + 2;
    int li = (lane < 62) ? lane : 0;
    ushort craw = slots[li];
    int cli = (lane < deg) ? (int)craw : 0;
    float nl = (lane < deg) ? nrm[cli] : 0.0f;

    float ax = 0.0f, ay = 0.0f;
    for (int j = 0; j < deg; j += 8) {
#pragma unroll
        for (int u = 0; u < 8; ++u) {
            int cc = __shfl(cli, j + u);
            float nn = __shfl(nl, j + u);             // 0 for slots >= deg
            ushort2 v = ((const ushort2*)(xb + (size_t)cc * CH))[lane];
            ax = fmaf(bf2f((uint)v.x), nn, ax);
            ay = fmaf(bf2f((uint)v.y), nn, ay);
        }
    }

    ushort2 hv;
    hv.x = f2bf(ax * dr);
    hv.y = f2bf(ay * dr);
    ((ushort2*)(ahi + (size_t)node * CH))[lane] = hv;
}

// ---------------- MFMA GEMM: out = Ahi @ (Whi+Wlo)^T + b, 32 rows/block ----------------
// B frags (W hi/lo) reused across two 16-row A tiles -> half the W L2 traffic.
__global__ __launch_bounds__(256) void k_mfma(const ushort* __restrict__ ahi,
                                              const ushort* __restrict__ whi,
                                              const ushort* __restrict__ wlo,
                                              const float* __restrict__ bias,
                                              float* __restrict__ out) {
    const int wave = threadIdx.x >> 6;
    const int lane = threadIdx.x & 63;
    const int quad = lane >> 4;
    const int r16 = lane & 15;
    const int m0 = blockIdx.x * 32;            // 1563 blocks; last block predicated
    const int nt0 = wave * 2, nt1 = nt0 + 1;

    const ushort* a0p  = ahi + (size_t)(m0 + r16) * CH + quad * 8;
    const ushort* a1p  = a0p + 16 * CH;
    const ushort* bh0p = whi + (size_t)(nt0 * 16 + r16) * CH + quad * 8;
    const ushort* bl0p = wlo + (size_t)(nt0 * 16 + r16) * CH + quad * 8;
    const ushort* bh1p = whi + (size_t)(nt1 * 16 + r16) * CH + quad * 8;
    const ushort* bl1p = wlo + (size_t)(nt1 * 16 + r16) * CH + quad * 8;

    float b0 = bias[nt0 * 16 + r16];
    float b1 = bias[nt1 * 16 + r16];
    floatx4 acc00 = {b0, b0, b0, b0};   // rows 0-15,  cols nt0
    floatx4 acc01 = {b1, b1, b1, b1};   // rows 0-15,  cols nt1
    floatx4 acc10 = {b0, b0, b0, b0};   // rows 16-31, cols nt0
    floatx4 acc11 = {b1, b1, b1, b1};   // rows 16-31, cols nt1

#pragma unroll
    for (int kb = 0; kb < 4; ++kb) {
        const int k0 = kb * 32;
        short8 a0 = *(const short8*)(a0p + k0);
        short8 a1 = *(const short8*)(a1p + k0);
        short8 h0 = *(const short8*)(bh0p + k0);
        short8 l0 = *(const short8*)(bl0p + k0);
        short8 h1 = *(const short8*)(bh1p + k0);
        short8 l1 = *(const short8*)(bl1p + k0);
        acc00 = __builtin_amdgcn_mfma_f32_16x16x32_bf16(a0, h0, acc00, 0, 0, 0);
        acc00 = __builtin_amdgcn_mfma_f32_16x16x32_bf16(a0, l0, acc00, 0, 0, 0);
        acc01 = __builtin_amdgcn_mfma_f32_16x16x32_bf16(a0, h1, acc01, 0, 0, 0);
        acc01 = __builtin_amdgcn_mfma_f32_16x16x32_bf16(a0, l1, acc01, 0, 0, 0);
        acc10 = __builtin_amdgcn_mfma_f32_16x16x32_bf16(a1, h0, acc10, 0, 0, 0);
        acc10 = __builtin_amdgcn_mfma_f32_16x16x32_bf16(a1, l0, acc10, 0, 0, 0);
        acc11 = __builtin_amdgcn_mfma_f32_16x16x32_bf16(a1, h1, acc11, 0, 0, 0);
        acc11 = __builtin_amdgcn_mfma_f32_16x16x32_bf16(a1, l1, acc11, 0, 0, 0);
    }

#pragma unroll
    for (int r = 0; r < 4; ++r) {
        int row0 = m0 + quad * 4 + r;
        int row1 = row0 + 16;
        if (row0 < NN) {
            out[(size_t)row0 * CH + nt0 * 16 + r16] = acc00[r];
            out[(size_t)row0 * CH + nt1 * 16 + r16] = acc01[r];
        }
        if (row1 < NN) {
            out[(size_t)row1 * CH + nt0 * 16 + r16] = acc10[r];
            out[(size_t)row1 * CH + nt1 * 16 + r16] = acc11[r];
        }
    }
}

extern "C" void kernel_launch(void* const* d_in, const int* in_sizes, int n_in,
                              void* d_out, int out_size, void* d_ws, size_t ws_size,
                              hipStream_t stream) {
    const float* x = (const float*)d_in[0];
    const int* ei = (const int*)d_in[1]; // [2, NE]: row = ei, col = ei + NE
    const float* W = (const float*)d_in[2];
    const float* b = (const float*)d_in[3];
    float* out = (float*)d_out;

    // ws: [csr NN*32 uint = 6.4MB][deg_c 50176 int][nrm 50176 f32]
    //     [ahi (NN+16)*CH u16][xb NN*CH u16][whi 16384 u16][wlo 16384 u16]
    uint* csr = (uint*)d_ws;
    int* deg_c = (int*)(csr + (size_t)NN * RSTR);
    float* nrm = (float*)(deg_c + 50176);
    ushort* ahi = (ushort*)(nrm + 50176);
    ushort* xb = ahi + (size_t)(NN + 16) * CH;
    ushort* whi = xb + (size_t)NN * CH;
    ushort* wlo = whi + CH * CH;

    hipMemsetAsync(csr, 0, (size_t)NN * RSTR * sizeof(uint), stream);
    k_prep<<<6620, 256, 0, stream>>>(x, xb, W, whi, wlo, ei, ei + NE, csr);
    k_nrm<<<196, 256, 0, stream>>>(csr, deg_c, nrm);
    k_agg<<<NN / 4, 256, 0, stream>>>(xb, deg_c, nrm, csr, ahi);
    k_mfma<<<(NN + 31) / 32, 256, 0, stream>>>(ahi, whi, wlo, b, out);
}